// Round 5
// baseline (1544.030 us; speedup 1.0000x reference)
//
#include <hip/hip_runtime.h>

#define BB 64
#define TT 1024
#define HH 1024
#define II 8
#define OO 8
#define RRK 4
#define NOISE_STD 0.05f
#define ALPHA 0.2f

typedef float v4f __attribute__((ext_vector_type(4)));

// 2*log2(e): tanh argument scale so exp goes through native v_exp_f32 (2^x).
#define C2E 2.885390081777927f

// DPP-based add: acc + dpp_perm(src). VALU pipe.
template<int CTRL, int RM>
__device__ __forceinline__ float dpp_add(float acc, float src) {
    int s = __builtin_amdgcn_update_dpp(0, __float_as_int(src), CTRL, RM, 0xF, true);
    return acc + __int_as_float(s);
}

// Full wave64 sum; result valid on lane 63 only (prew's reduce).
__device__ __forceinline__ float wave_sum(float x) {
    x = dpp_add<0xB1, 0xF>(x, x);   // xor 1
    x = dpp_add<0x4E, 0xF>(x, x);   // xor 2
    x = dpp_add<0x141, 0xF>(x, x);  // row_half_mirror
    x = dpp_add<0x140, 0xF>(x, x);  // row_mirror
    x = dpp_add<0x142, 0xA>(x, x);  // row_bcast:15
    x = dpp_add<0x143, 0xC>(x, x);  // row_bcast:31
    return x;
}

// Full wave64 sum, ALL lanes valid: symmetric butterfly.
// Stages 1-4 are involutions (xor1, xor2, mirror8, mirror16) -> sum-of-16
// valid in every lane; then xor16/xor32 via bpermute-backed shfl.
__device__ __forceinline__ float wave_sum_all(float x) {
    x = dpp_add<0xB1, 0xF>(x, x);   // + lane^1
    x = dpp_add<0x4E, 0xF>(x, x);   // + lane^2
    x = dpp_add<0x141, 0xF>(x, x);  // + mirror in 8  (crosses quads)
    x = dpp_add<0x140, 0xF>(x, x);  // + mirror in 16 (crosses 8s)
    x += __shfl_xor(x, 16);
    x += __shfl_xor(x, 32);
    return x;
}

// tanh(x) = 1 - 2/(1 + 2^(2x*log2e)); argument passed as 2x*log2(e).
__device__ __forceinline__ float tanh_from_l2x(float l2x) {
    float e = __builtin_amdgcn_exp2f(l2x);
    float r = __builtin_amdgcn_rcpf(e + 1.0f);
    return fmaf(-2.0f, r, 1.0f);
}

// Barrier WITHOUT the vmcnt(0) drain of __syncthreads(): waits only LDS ops.
__device__ __forceinline__ void block_sync_lds() {
    asm volatile("s_waitcnt lgkmcnt(0)\n\ts_barrier" ::: "memory");
}

// Same-wave LDS write->read ordering fence (single-wave kernel: no barrier).
__device__ __forceinline__ void lds_fence() {
    asm volatile("s_waitcnt lgkmcnt(0)" ::: "memory");
}

// ---------------------------------------------------------------------------
// Pre-kernel: W[row][o] = NOISE_STD * sum_h noise[row,h] * wo[h][o]*so[o]
// (unchanged from round 4 — proven)
// ---------------------------------------------------------------------------
__global__ __launch_bounds__(256)
void prew_kernel(const float* __restrict__ noise, const float* __restrict__ wo,
                 const float* __restrict__ so, float* __restrict__ W) {
    __shared__ __align__(16) float red[2][8][4][8];   // ring x row x wave x o

    const int tid  = threadIdx.x;
    const int wave = tid >> 6;
    const int lane = tid & 63;
    const int e0   = tid << 2;                        // h = e0..e0+3

    float woa[4][OO];
    {
        float so8[OO];
        #pragma unroll
        for (int o = 0; o < OO; ++o) so8[o] = so[o] * NOISE_STD;
        #pragma unroll
        for (int e = 0; e < 4; ++e) {
            const float4 a4 = *(const float4*)(wo + (e0 + e) * OO);
            const float4 b4 = *(const float4*)(wo + (e0 + e) * OO + 4);
            woa[e][0] = a4.x * so8[0]; woa[e][1] = a4.y * so8[1];
            woa[e][2] = a4.z * so8[2]; woa[e][3] = a4.w * so8[3];
            woa[e][4] = b4.x * so8[4]; woa[e][5] = b4.y * so8[5];
            woa[e][6] = b4.z * so8[6]; woa[e][7] = b4.w * so8[7];
        }
    }

    const int row0 = blockIdx.x * 32;
    float4 nz[8], nzn[8];
    #pragma unroll
    for (int j = 0; j < 8; ++j)
        nz[j] = *(const float4*)(noise + (size_t)(row0 + j) * HH + e0);

    #pragma unroll
    for (int ph = 0; ph < 4; ++ph) {
        const int cur   = ph & 1;
        const int rbase = row0 + ph * 8;

        if (ph < 3) {
            #pragma unroll
            for (int j = 0; j < 8; ++j)
                nzn[j] = *(const float4*)(noise + (size_t)(rbase + 8 + j) * HH + e0);
        }

        #pragma unroll
        for (int j = 0; j < 8; ++j) {
            float op[OO];
            #pragma unroll
            for (int o = 0; o < OO; ++o)
                op[o] = fmaf(nz[j].x, woa[0][o], fmaf(nz[j].y, woa[1][o],
                        fmaf(nz[j].z, woa[2][o], nz[j].w * woa[3][o])));
            #pragma unroll
            for (int o = 0; o < OO; ++o) op[o] = wave_sum(op[o]);
            if (lane == 63) {
                *(float4*)&red[cur][j][wave][0] = make_float4(op[0], op[1], op[2], op[3]);
                *(float4*)&red[cur][j][wave][4] = make_float4(op[4], op[5], op[6], op[7]);
            }
        }
        block_sync_lds();
        if (tid < 64) {
            const int j = tid >> 3, o = tid & 7;
            W[(rbase + j) * OO + o] = (red[cur][j][0][o] + red[cur][j][1][o]) +
                                      (red[cur][j][2][o] + red[cur][j][3][o]);
        }
        #pragma unroll
        for (int j = 0; j < 8; ++j) nz[j] = nzn[j];
    }
}

// ---------------------------------------------------------------------------
// Main RNN kernel: ONE WAVE per batch (64 threads, 16 hidden elems/lane).
// Rationale (r2/r3/r4 post-mortems): every multi-wave config pays ~700 cy/step
// of cross-wave exchange stall (ds_write -> barrier -> ds_read + convoying),
// regardless of elems/lane. Single wave: the H=1024 reduction is a pure
// in-register butterfly (4 DPP + 2 shfl_xor), NO barriers in the whole loop.
// y-recurrence stays out of the loop (chunk-scan post-pass over logged v_t).
// ---------------------------------------------------------------------------
__global__ __launch_bounds__(64, 1)
void rnn_seq_kernel(const float* __restrict__ x, const float* __restrict__ noise,
                    const float* __restrict__ wi, const float* __restrict__ si,
                    const float* __restrict__ mM, const float* __restrict__ nM,
                    const float* __restrict__ bv, const float* __restrict__ wo,
                    const float* __restrict__ so, const float* __restrict__ h0,
                    const float* __restrict__ W, float* __restrict__ out) {
    __shared__ __align__(16) float lds_x[(TT + 1) * II];  // 32.03 KB (+pad row)
    __shared__ __align__(16) float lds_W[TT * OO];        // 32 KB
    __shared__ __align__(16) float lds_v[TT * RRK];       // 16 KB (v_t log)
    __shared__ float ambx[104];                           // Am(32)|Bx(64)|y0(8)
    __shared__ float chs[8][OO];                          // post-pass carries

    const int lane = threadIdx.x;                         // 64 threads = 1 wave
    const int b    = blockIdx.x;
    const int e0   = lane << 4;                           // 16 elems per lane
    const int oc   = lane & 7;

    // ---- stage x[b] (+pad) and W[b] into LDS ----
    {
        const float4* sx = (const float4*)(x + (size_t)b * (TT * II));
        const float4* sw = (const float4*)(W + (size_t)b * (TT * OO));
        float4* dx = (float4*)lds_x;
        float4* dw = (float4*)lds_W;
        #pragma unroll
        for (int k = 0; k < 32; ++k) {
            dx[k * 64 + lane] = sx[k * 64 + lane];
            dw[k * 64 + lane] = sw[k * 64 + lane];
        }
        if (lane < 2) dx[2048 + lane] = sx[2046 + lane];  // pad row TT = TT-1
    }

    // ---- loop weights (per-lane, elems e0..e0+15 grouped g=0..3) ----
    v4f wia[II][4];                       // ALPHA*si[i]*wi[i][e0+g*4..+3]
    #pragma unroll
    for (int i = 0; i < II; ++i) {
        const float s = ALPHA * si[i];
        #pragma unroll
        for (int g = 0; g < 4; ++g)
            wia[i][g] = s * *(const v4f*)(wi + (size_t)i * HH + e0 + g * 4);
    }
    v4f mag[4][RRK];                      // (ALPHA/H)*m, column q, group g
    {
        const float cs = ALPHA / (float)HH;
        v4f mrow[16];
        #pragma unroll
        for (int e = 0; e < 16; ++e)
            mrow[e] = cs * *(const v4f*)(mM + (size_t)(e0 + e) * RRK);
        #pragma unroll
        for (int g = 0; g < 4; ++g) {
            #pragma unroll
            for (int q = 0; q < RRK; ++q)
                mag[g][q] = (v4f){mrow[g*4+0][q], mrow[g*4+1][q],
                                  mrow[g*4+2][q], mrow[g*4+3][q]};
        }
    }
    v4f h[4], r[4], tb[4];
    #pragma unroll
    for (int g = 0; g < 4; ++g) {
        h[g]  = *(const v4f*)(h0 + e0 + g * 4);
        tb[g] = C2E * *(const v4f*)(bv + e0 + g * 4);
        const v4f tg = C2E * h[g];
        r[g].x = tanh_from_l2x(tg.x); r[g].y = tanh_from_l2x(tg.y);
        r[g].z = tanh_from_l2x(tg.z); r[g].w = tanh_from_l2x(tg.w);
    }

    // ---- preamble: Am (4x8), Bx (8x8), y0 (8) via all-lane butterfly ----
    {
        float woa[16][OO];                // wo[e][o]*so[o] (transient)
        #pragma unroll
        for (int e = 0; e < 16; ++e) {
            const float4 a4 = *(const float4*)(wo + (size_t)(e0 + e) * OO);
            const float4 b4 = *(const float4*)(wo + (size_t)(e0 + e) * OO + 4);
            woa[e][0] = a4.x * so[0]; woa[e][1] = a4.y * so[1];
            woa[e][2] = a4.z * so[2]; woa[e][3] = a4.w * so[3];
            woa[e][4] = b4.x * so[4]; woa[e][5] = b4.y * so[5];
            woa[e][6] = b4.z * so[6]; woa[e][7] = b4.w * so[7];
        }
        #pragma unroll
        for (int kg = 0; kg < 26; ++kg) {
            float p[4];
            #pragma unroll
            for (int u = 0; u < 4; ++u) {
                const int k = kg * 4 + u;
                float s = 0.0f;
                if (k < 32) {
                    const int q = k >> 3, o = k & 7;
                    #pragma unroll
                    for (int g = 0; g < 4; ++g) {
                        s = fmaf(mag[g][q].x, woa[g*4+0][o], s);
                        s = fmaf(mag[g][q].y, woa[g*4+1][o], s);
                        s = fmaf(mag[g][q].z, woa[g*4+2][o], s);
                        s = fmaf(mag[g][q].w, woa[g*4+3][o], s);
                    }
                } else if (k < 96) {
                    const int i = (k - 32) >> 3, o = k & 7;
                    #pragma unroll
                    for (int g = 0; g < 4; ++g) {
                        s = fmaf(wia[i][g].x, woa[g*4+0][o], s);
                        s = fmaf(wia[i][g].y, woa[g*4+1][o], s);
                        s = fmaf(wia[i][g].z, woa[g*4+2][o], s);
                        s = fmaf(wia[i][g].w, woa[g*4+3][o], s);
                    }
                } else {
                    const int o = k - 96;
                    #pragma unroll
                    for (int g = 0; g < 4; ++g) {
                        s = fmaf(h[g].x, woa[g*4+0][o], s);
                        s = fmaf(h[g].y, woa[g*4+1][o], s);
                        s = fmaf(h[g].z, woa[g*4+2][o], s);
                        s = fmaf(h[g].w, woa[g*4+3][o], s);
                    }
                }
                p[u] = wave_sum_all(s);
            }
            if (lane == 0)
                *(v4f*)&ambx[kg * 4] = (v4f){p[0], p[1], p[2], p[3]};
        }
    }
    v4f nrv[16];                          // n rows (v4 over q) — load after
    #pragma unroll                        // preamble to limit peak pressure
    for (int e = 0; e < 16; ++e)
        nrv[e] = *(const v4f*)(nM + (size_t)(e0 + e) * RRK);

    lds_fence();                          // staging visible to own reads

    // ---- pipelined operand state ----
    const float* nzp = noise + (size_t)b * (TT * HH) + e0;
    v4f nzA[4], nzB[4];
    #pragma unroll
    for (int g = 0; g < 4; ++g) {
        nzA[g] = *(const v4f*)(nzp + g * 4);
        nzB[g] = *(const v4f*)(nzp + (size_t)HH + g * 4);
    }
    v4f xc0 = *(const v4f*)&lds_x[0];
    v4f xc1 = *(const v4f*)&lds_x[4];

#define RNN_STEP(t, NZ)                                                        \
    {                                                                          \
        const v4f xn0 = *(const v4f*)&lds_x[((t) + 1) * II];                   \
        const v4f xn1 = *(const v4f*)&lds_x[((t) + 1) * II + 4];               \
        /* vp = n^T r over this lane's 16 elems (4 chains -> tree) */          \
        v4f c0 = r[0].x * nrv[0];  c0 += r[0].y * nrv[1];                      \
        c0 += r[0].z * nrv[2];     c0 += r[0].w * nrv[3];                      \
        v4f c1 = r[1].x * nrv[4];  c1 += r[1].y * nrv[5];                      \
        c1 += r[1].z * nrv[6];     c1 += r[1].w * nrv[7];                      \
        v4f c2 = r[2].x * nrv[8];  c2 += r[2].y * nrv[9];                      \
        c2 += r[2].z * nrv[10];    c2 += r[2].w * nrv[11];                     \
        v4f c3 = r[3].x * nrv[12]; c3 += r[3].y * nrv[13];                     \
        c3 += r[3].z * nrv[14];    c3 += r[3].w * nrv[15];                     \
        const v4f vp = (c0 + c1) + (c2 + c3);                                  \
        const float v0 = wave_sum_all(vp.x);                                   \
        const float v1 = wave_sum_all(vp.y);                                   \
        const float v2 = wave_sum_all(vp.z);                                   \
        const float v3 = wave_sum_all(vp.w);                                   \
        if (lane == 0)                                                         \
            *(v4f*)&lds_v[(t) * RRK] = (v4f){v0, v1, v2, v3};                  \
        /* h update: au + m.v, then decay + noise */                           \
        _Pragma("unroll")                                                      \
        for (int g = 0; g < 4; ++g) {                                          \
            v4f a = xc0.x * wia[0][g];                                         \
            a += xc0.y * wia[1][g];  a += xc0.z * wia[2][g];                   \
            a += xc0.w * wia[3][g];  a += xc1.x * wia[4][g];                   \
            a += xc1.y * wia[5][g];  a += xc1.z * wia[6][g];                   \
            a += xc1.w * wia[7][g];                                            \
            a += v0 * mag[g][0];     a += v1 * mag[g][1];                      \
            a += v2 * mag[g][2];     a += v3 * mag[g][3];                      \
            h[g] = (1.0f - ALPHA) * h[g] + a;                                  \
            h[g] += NOISE_STD * NZ[g];                                         \
        }                                                                      \
        /* prefetch noise for t+2 into NZ (clamped; clamp rows unused) */      \
        {                                                                      \
            const int tf = ((t) + 2 < TT) ? (t) + 2 : TT - 1;                  \
            const float* np = nzp + (size_t)tf * HH;                           \
            _Pragma("unroll")                                                  \
            for (int g = 0; g < 4; ++g) NZ[g] = *(const v4f*)(np + g * 4);     \
        }                                                                      \
        /* r = tanh(h + b) */                                                  \
        _Pragma("unroll")                                                      \
        for (int g = 0; g < 4; ++g) {                                          \
            const v4f tg = C2E * h[g] + tb[g];                                 \
            r[g].x = tanh_from_l2x(tg.x); r[g].y = tanh_from_l2x(tg.y);        \
            r[g].z = tanh_from_l2x(tg.z); r[g].w = tanh_from_l2x(tg.w);        \
        }                                                                      \
        xc0 = xn0; xc1 = xn1;                                                  \
    }

    for (int t = 0; t < TT; t += 2) {
        RNN_STEP(t, nzA)
        RNN_STEP(t + 1, nzB)
    }
#undef RNN_STEP

    // ---- post-pass: y_t = 0.8*y_{t-1} + (x_t.Bx + W_t + v_t.Am) ----
    lds_fence();                          // lds_v / ambx writes -> reads

    float Amr[RRK], Bxr[II];
    #pragma unroll
    for (int q = 0; q < RRK; ++q) Amr[q] = ambx[q * 8 + oc];
    #pragma unroll
    for (int i = 0; i < II; ++i) Bxr[i] = ambx[32 + i * 8 + oc];

    const int c   = lane >> 3;            // chunk 0..7, 128 t each
    const int tc  = c * 128;
    float a128;
    {
        float a = 1.0f - ALPHA;
        #pragma unroll
        for (int k = 0; k < 7; ++k) a = a * a;   // 0.8^128
        a128 = a;
    }

    auto step_s = [&](int t) -> float {
        const v4f xa  = *(const v4f*)&lds_x[t * II];
        const v4f xb2 = *(const v4f*)&lds_x[t * II + 4];
        const v4f vv  = *(const v4f*)&lds_v[t * RRK];
        float s = lds_W[t * OO + oc];
        s = fmaf(xa.x,  Bxr[0], s); s = fmaf(xa.y,  Bxr[1], s);
        s = fmaf(xa.z,  Bxr[2], s); s = fmaf(xa.w,  Bxr[3], s);
        s = fmaf(xb2.x, Bxr[4], s); s = fmaf(xb2.y, Bxr[5], s);
        s = fmaf(xb2.z, Bxr[6], s); s = fmaf(xb2.w, Bxr[7], s);
        s = fmaf(vv.x,  Amr[0], s); s = fmaf(vv.y,  Amr[1], s);
        s = fmaf(vv.z,  Amr[2], s); s = fmaf(vv.w,  Amr[3], s);
        return s;
    };

    float L = 0.0f;
    #pragma unroll 4
    for (int jt = 0; jt < 128; ++jt)
        L = fmaf(1.0f - ALPHA, L, step_s(tc + jt));
    chs[c][oc] = L;
    lds_fence();
    if (lane < OO) {                      // exact serial carry over 8 chunks
        float Y = ambx[96 + lane];        // y_{-1} = h0 . wo_full
        #pragma unroll
        for (int c2 = 0; c2 < 8; ++c2) {
            const float Lc = chs[c2][lane];
            chs[c2][lane] = Y;
            Y = fmaf(a128, Y, Lc);
        }
    }
    lds_fence();
    float yv = chs[c][oc];
    float* ob = out + (size_t)b * (TT * OO);
    #pragma unroll 4
    for (int jt = 0; jt < 128; ++jt) {
        const int t = tc + jt;
        yv = fmaf(1.0f - ALPHA, yv, step_s(t));
        ob[t * OO + oc] = yv;
    }
}

extern "C" void kernel_launch(void* const* d_in, const int* in_sizes, int n_in,
                              void* d_out, int out_size, void* d_ws, size_t ws_size,
                              hipStream_t stream) {
    const float* x     = (const float*)d_in[0];
    const float* noise = (const float*)d_in[1];
    const float* wi    = (const float*)d_in[2];
    const float* si    = (const float*)d_in[3];
    const float* mM    = (const float*)d_in[4];
    const float* nM    = (const float*)d_in[5];
    const float* bv    = (const float*)d_in[6];
    const float* wo    = (const float*)d_in[7];
    const float* so    = (const float*)d_in[8];
    const float* h0    = (const float*)d_in[9];
    float* out = (float*)d_out;
    float* W   = (float*)d_ws;   // 65536 x 8 fp32 = 2 MB

    prew_kernel<<<dim3(2048), dim3(256), 0, stream>>>(noise, wo, so, W);
    rnn_seq_kernel<<<dim3(BB), dim3(64), 0, stream>>>(
        x, noise, wi, si, mM, nM, bv, wo, so, h0, W, out);
}

// Round 6
// 932.691 us; speedup vs baseline: 1.6555x; 1.6555x over previous
//
#include <hip/hip_runtime.h>

#define BB 64
#define TT 1024
#define HH 1024
#define II 8
#define OO 8
#define RRK 4
#define NOISE_STD 0.05f
#define ALPHA 0.2f

typedef float v4f __attribute__((ext_vector_type(4)));

// 2*log2(e): tanh argument scale so exp goes through native v_exp_f32 (2^x).
#define C2E 2.885390081777927f

// DPP-based add: acc + dpp_perm(src). VALU pipe (NOT ds_bpermute).
template<int CTRL, int RM>
__device__ __forceinline__ float dpp_add(float acc, float src) {
    int s = __builtin_amdgcn_update_dpp(0, __float_as_int(src), CTRL, RM, 0xF, true);
    return acc + __int_as_float(s);
}

// Full wave64 sum; result valid on lane 63. All-VALU (6 DPP adds).
__device__ __forceinline__ float wave_sum(float x) {
    x = dpp_add<0xB1, 0xF>(x, x);   // xor 1
    x = dpp_add<0x4E, 0xF>(x, x);   // xor 2
    x = dpp_add<0x141, 0xF>(x, x);  // row_half_mirror
    x = dpp_add<0x140, 0xF>(x, x);  // row_mirror
    x = dpp_add<0x142, 0xA>(x, x);  // row_bcast:15
    x = dpp_add<0x143, 0xC>(x, x);  // row_bcast:31
    return x;
}

// Uniform broadcast of lane 63's value -> SGPR (free broadcast as VALU operand).
__device__ __forceinline__ float rl63(float x) {
    return __int_as_float(__builtin_amdgcn_readlane(__float_as_int(x), 63));
}

// tanh(x) = 1 - 2/(1 + 2^(2x*log2e)); argument passed as 2x*log2(e).
__device__ __forceinline__ float tanh_from_l2x(float l2x) {
    float e = __builtin_amdgcn_exp2f(l2x);
    float r = __builtin_amdgcn_rcpf(e + 1.0f);
    return fmaf(-2.0f, r, 1.0f);
}

// Barrier WITHOUT the vmcnt(0) drain of __syncthreads(): waits only LDS ops.
__device__ __forceinline__ void block_sync_lds() {
    asm volatile("s_waitcnt lgkmcnt(0)\n\ts_barrier" ::: "memory");
}

// Same-wave LDS write->read ordering fence (single-wave kernel: no barrier).
__device__ __forceinline__ void lds_fence() {
    asm volatile("s_waitcnt lgkmcnt(0)" ::: "memory");
}

// ===========================================================================
// PATH A (needs 258 MB workspace): d-stream design.
//   pre_d_kernel : d[row][h] = alpha*(x@si*wi)[h] + sigma*noise[row][h]
//                  sbase[row][o] = d[row][:] . (wo[:,o]*so[o])
//   rnn_d_kernel : single wave per batch, no barriers, no wia/au in loop,
//                  all-VALU reduce + readlane broadcast, y via post-pass scan.
// ===========================================================================

__global__ __launch_bounds__(256)
void pre_d_kernel(const float* __restrict__ x, const float* __restrict__ noise,
                  const float* __restrict__ wi, const float* __restrict__ si,
                  const float* __restrict__ wo, const float* __restrict__ so,
                  float* __restrict__ d, float* __restrict__ sbase) {
    __shared__ __align__(16) float red[2][8][4][8];   // ring x row x wave x o

    const int tid  = threadIdx.x;
    const int wave = tid >> 6;
    const int lane = tid & 63;
    const int e0   = tid << 2;                        // h = e0..e0+3

    // wia4[i] = ALPHA*si[i]*wi[i][e0..e0+3]
    v4f wia4[II];
    #pragma unroll
    for (int i = 0; i < II; ++i)
        wia4[i] = (ALPHA * si[i]) * *(const v4f*)(wi + (size_t)i * HH + e0);

    // woa[e][o] = wo[e0+e][o]*so[o]   (NO sigma: sigma lives inside d via noise)
    float woa[4][OO];
    #pragma unroll
    for (int e = 0; e < 4; ++e) {
        const float4 a4 = *(const float4*)(wo + (e0 + e) * OO);
        const float4 b4 = *(const float4*)(wo + (e0 + e) * OO + 4);
        woa[e][0] = a4.x * so[0]; woa[e][1] = a4.y * so[1];
        woa[e][2] = a4.z * so[2]; woa[e][3] = a4.w * so[3];
        woa[e][4] = b4.x * so[4]; woa[e][5] = b4.y * so[5];
        woa[e][6] = b4.z * so[6]; woa[e][7] = b4.w * so[7];
    }

    const int row0 = blockIdx.x * 32;
    float4 nz[8], nzn[8];
    #pragma unroll
    for (int j = 0; j < 8; ++j)
        nz[j] = *(const float4*)(noise + (size_t)(row0 + j) * HH + e0);

    #pragma unroll
    for (int ph = 0; ph < 4; ++ph) {
        const int cur   = ph & 1;
        const int rbase = row0 + ph * 8;

        if (ph < 3) {
            #pragma unroll
            for (int j = 0; j < 8; ++j)
                nzn[j] = *(const float4*)(noise + (size_t)(rbase + 8 + j) * HH + e0);
        }

        #pragma unroll
        for (int j = 0; j < 8; ++j) {
            const int row = rbase + j;
            // x row (8 floats, same addr across lanes -> broadcast load)
            const float4 xr0 = *(const float4*)(x + (size_t)row * II);
            const float4 xr1 = *(const float4*)(x + (size_t)row * II + 4);
            v4f u = xr0.x * wia4[0];
            u += xr0.y * wia4[1];  u += xr0.z * wia4[2];
            u += xr0.w * wia4[3];  u += xr1.x * wia4[4];
            u += xr1.y * wia4[5];  u += xr1.z * wia4[6];
            u += xr1.w * wia4[7];
            v4f d4 = u;
            d4.x = fmaf(NOISE_STD, nz[j].x, d4.x);
            d4.y = fmaf(NOISE_STD, nz[j].y, d4.y);
            d4.z = fmaf(NOISE_STD, nz[j].z, d4.z);
            d4.w = fmaf(NOISE_STD, nz[j].w, d4.w);
            *(v4f*)(d + (size_t)row * HH + e0) = d4;

            float op[OO];
            #pragma unroll
            for (int o = 0; o < OO; ++o)
                op[o] = fmaf(d4.x, woa[0][o], fmaf(d4.y, woa[1][o],
                        fmaf(d4.z, woa[2][o], d4.w * woa[3][o])));
            #pragma unroll
            for (int o = 0; o < OO; ++o) op[o] = wave_sum(op[o]);
            if (lane == 63) {
                *(float4*)&red[cur][j][wave][0] = make_float4(op[0], op[1], op[2], op[3]);
                *(float4*)&red[cur][j][wave][4] = make_float4(op[4], op[5], op[6], op[7]);
            }
        }
        block_sync_lds();
        if (tid < 64) {
            const int j = tid >> 3, o = tid & 7;
            sbase[(rbase + j) * OO + o] = (red[cur][j][0][o] + red[cur][j][1][o]) +
                                          (red[cur][j][2][o] + red[cur][j][3][o]);
        }
        #pragma unroll
        for (int j = 0; j < 8; ++j) nz[j] = nzn[j];
    }
}

__global__ __launch_bounds__(64, 1)
void rnn_d_kernel(const float* __restrict__ d, const float* __restrict__ sbase,
                  const float* __restrict__ mM, const float* __restrict__ nM,
                  const float* __restrict__ bv, const float* __restrict__ wo,
                  const float* __restrict__ so, const float* __restrict__ h0,
                  float* __restrict__ out) {
    __shared__ __align__(16) float lds_sb[TT * OO];   // 32 KB (sbase rows)
    __shared__ __align__(16) float lds_v[TT * RRK];   // 16 KB (v_t log)
    __shared__ __align__(16) float amy[40];           // Am(32) | y0(8)
    __shared__ float chs[8][OO];                      // post-pass carries

    const int lane = threadIdx.x;                     // 64 threads = 1 wave
    const int b    = blockIdx.x;
    const int e0   = lane << 4;                       // 16 elems per lane
    const int oc   = lane & 7;

    // ---- stage sbase[b] into LDS ----
    {
        const float4* ss = (const float4*)(sbase + (size_t)b * (TT * OO));
        float4* dsb = (float4*)lds_sb;
        #pragma unroll
        for (int k = 0; k < 32; ++k)
            dsb[k * 64 + lane] = ss[k * 64 + lane];
    }

    // ---- loop weights (per-lane, 16 elems grouped g=0..3) ----
    v4f mag[4][RRK];                      // (ALPHA/H)*m, column q, group g
    {
        const float cs = ALPHA / (float)HH;
        #pragma unroll
        for (int g = 0; g < 4; ++g) {
            v4f m0 = cs * *(const v4f*)(mM + (size_t)(e0 + g*4 + 0) * RRK);
            v4f m1 = cs * *(const v4f*)(mM + (size_t)(e0 + g*4 + 1) * RRK);
            v4f m2 = cs * *(const v4f*)(mM + (size_t)(e0 + g*4 + 2) * RRK);
            v4f m3 = cs * *(const v4f*)(mM + (size_t)(e0 + g*4 + 3) * RRK);
            #pragma unroll
            for (int q = 0; q < RRK; ++q)
                mag[g][q] = (v4f){m0[q], m1[q], m2[q], m3[q]};
        }
    }
    v4f h[4], r[4], tb[4];
    #pragma unroll
    for (int g = 0; g < 4; ++g) {
        h[g]  = *(const v4f*)(h0 + e0 + g * 4);
        tb[g] = C2E * *(const v4f*)(bv + e0 + g * 4);
        const v4f tg = C2E * h[g];
        r[g].x = tanh_from_l2x(tg.x); r[g].y = tanh_from_l2x(tg.y);
        r[g].z = tanh_from_l2x(tg.z); r[g].w = tanh_from_l2x(tg.w);
    }

    // ---- preamble: Am[q][o] = sum_h (cs*m)[h][q]*wo'[h][o]; y0 = h0.wo' ----
    // wo rows loaded on the fly (no 128-reg woa array -> no pressure spike).
    {
        float acc[40];
        #pragma unroll
        for (int k = 0; k < 40; ++k) acc[k] = 0.0f;
        float so8[OO];
        #pragma unroll
        for (int o = 0; o < OO; ++o) so8[o] = so[o];
        #pragma unroll
        for (int e = 0; e < 16; ++e) {
            const int g = e >> 2, eg = e & 3;
            const float4 a4 = *(const float4*)(wo + (size_t)(e0 + e) * OO);
            const float4 b4 = *(const float4*)(wo + (size_t)(e0 + e) * OO + 4);
            float wp[OO];
            wp[0] = a4.x * so8[0]; wp[1] = a4.y * so8[1];
            wp[2] = a4.z * so8[2]; wp[3] = a4.w * so8[3];
            wp[4] = b4.x * so8[4]; wp[5] = b4.y * so8[5];
            wp[6] = b4.z * so8[6]; wp[7] = b4.w * so8[7];
            #pragma unroll
            for (int q = 0; q < RRK; ++q) {
                const float ms = mag[g][q][eg];
                #pragma unroll
                for (int o = 0; o < OO; ++o)
                    acc[q * 8 + o] = fmaf(ms, wp[o], acc[q * 8 + o]);
            }
            const float hs = h[g][eg];
            #pragma unroll
            for (int o = 0; o < OO; ++o)
                acc[32 + o] = fmaf(hs, wp[o], acc[32 + o]);
        }
        #pragma unroll
        for (int k = 0; k < 40; ++k) acc[k] = wave_sum(acc[k]);
        if (lane == 63) {
            #pragma unroll
            for (int k = 0; k < 10; ++k)
                *(float4*)&amy[k * 4] = make_float4(acc[k*4+0], acc[k*4+1],
                                                    acc[k*4+2], acc[k*4+3]);
        }
    }

    // n rows (v4 over q) — loaded after preamble to limit peak pressure
    v4f nrv[16];
    #pragma unroll
    for (int e = 0; e < 16; ++e)
        nrv[e] = *(const v4f*)(nM + (size_t)(e0 + e) * RRK);

    // ---- pipelined d-stream state (prefetch distance 2) ----
    const float* dp = d + (size_t)b * (TT * HH) + e0;
    v4f dA[4], dB[4];
    #pragma unroll
    for (int g = 0; g < 4; ++g) {
        dA[g] = *(const v4f*)(dp + g * 4);
        dB[g] = *(const v4f*)(dp + (size_t)HH + g * 4);
    }

#define RNN_STEP(t, D, PF)                                                     \
    {                                                                          \
        /* vp = n^T r over this lane's 16 elems (4 chains -> tree) */          \
        v4f c0 = r[0].x * nrv[0];  c0 += r[0].y * nrv[1];                      \
        c0 += r[0].z * nrv[2];     c0 += r[0].w * nrv[3];                      \
        v4f c1 = r[1].x * nrv[4];  c1 += r[1].y * nrv[5];                      \
        c1 += r[1].z * nrv[6];     c1 += r[1].w * nrv[7];                      \
        v4f c2 = r[2].x * nrv[8];  c2 += r[2].y * nrv[9];                      \
        c2 += r[2].z * nrv[10];    c2 += r[2].w * nrv[11];                     \
        v4f c3 = r[3].x * nrv[12]; c3 += r[3].y * nrv[13];                     \
        c3 += r[3].z * nrv[14];    c3 += r[3].w * nrv[15];                     \
        const v4f vp = (c0 + c1) + (c2 + c3);                                  \
        /* all-VALU reduce to lane 63, then SGPR broadcast via readlane */     \
        const float s0 = wave_sum(vp.x);                                       \
        const float s1 = wave_sum(vp.y);                                       \
        const float s2 = wave_sum(vp.z);                                       \
        const float s3 = wave_sum(vp.w);                                       \
        if (lane == 63)                                                        \
            *(float4*)&lds_v[(t) * RRK] = make_float4(s0, s1, s2, s3);         \
        const float v0 = rl63(s0);                                             \
        const float v1 = rl63(s1);                                             \
        const float v2 = rl63(s2);                                             \
        const float v3 = rl63(s3);                                             \
        /* h = 0.8h + d_t + m.v  (d_t already contains alpha*u + sigma*nz) */  \
        _Pragma("unroll")                                                      \
        for (int g = 0; g < 4; ++g) {                                          \
            v4f a = D[g];                                                      \
            a += v0 * mag[g][0];   a += v1 * mag[g][1];                        \
            a += v2 * mag[g][2];   a += v3 * mag[g][3];                        \
            h[g] = (1.0f - ALPHA) * h[g] + a;                                  \
        }                                                                      \
        /* prefetch d row t+2 into D (consumed two steps later) */             \
        if (PF) {                                                              \
            const float* np = dp + (size_t)((t) + 2) * HH;                     \
            _Pragma("unroll")                                                  \
            for (int g = 0; g < 4; ++g) D[g] = *(const v4f*)(np + g * 4);      \
        }                                                                      \
        /* r = tanh(h + b) */                                                  \
        _Pragma("unroll")                                                      \
        for (int g = 0; g < 4; ++g) {                                          \
            const v4f tg = C2E * h[g] + tb[g];                                 \
            r[g].x = tanh_from_l2x(tg.x); r[g].y = tanh_from_l2x(tg.y);        \
            r[g].z = tanh_from_l2x(tg.z); r[g].w = tanh_from_l2x(tg.w);        \
        }                                                                      \
    }

    for (int t = 0; t < TT - 2; t += 2) {
        RNN_STEP(t,     dA, 1)
        RNN_STEP(t + 1, dB, 1)
    }
    RNN_STEP(TT - 2, dA, 0)
    RNN_STEP(TT - 1, dB, 0)
#undef RNN_STEP

    // ---- post-pass: y_t = 0.8*y_{t-1} + (sb_t + v_t.Am), exact chunk scan --
    lds_fence();                          // lds_v / amy / lds_sb -> reads

    float Amr[RRK];
    #pragma unroll
    for (int q = 0; q < RRK; ++q) Amr[q] = amy[q * 8 + oc];

    const int c  = lane >> 3;             // chunk 0..7, 128 t each
    const int tc = c * 128;
    float a128;
    {
        float a = 1.0f - ALPHA;
        #pragma unroll
        for (int k = 0; k < 7; ++k) a = a * a;   // 0.8^128
        a128 = a;
    }

    auto step_s = [&](int t) -> float {
        const v4f vv = *(const v4f*)&lds_v[t * RRK];
        float s = lds_sb[t * OO + oc];
        s = fmaf(vv.x, Amr[0], s); s = fmaf(vv.y, Amr[1], s);
        s = fmaf(vv.z, Amr[2], s); s = fmaf(vv.w, Amr[3], s);
        return s;
    };

    float L = 0.0f;
    #pragma unroll 4
    for (int jt = 0; jt < 128; ++jt)
        L = fmaf(1.0f - ALPHA, L, step_s(tc + jt));
    chs[c][oc] = L;
    lds_fence();
    if (lane < OO) {                      // exact serial carry over 8 chunks
        float Y = amy[32 + lane];         // y_{-1} = h0 . wo_full
        #pragma unroll
        for (int c2 = 0; c2 < 8; ++c2) {
            const float Lc = chs[c2][lane];
            chs[c2][lane] = Y;
            Y = fmaf(a128, Y, Lc);
        }
    }
    lds_fence();
    float yv = chs[c][oc];
    float* ob = out + (size_t)b * (TT * OO);
    #pragma unroll 4
    for (int jt = 0; jt < 128; ++jt) {
        const int t = tc + jt;
        yv = fmaf(1.0f - ALPHA, yv, step_s(t));
        ob[t * OO + oc] = yv;
    }
}

// ===========================================================================
// PATH B (fallback when workspace < 258 MB): proven round-2 kernels (400 us
// rnn + ~105 us prew). Verbatim from the best-measured configuration.
// ===========================================================================

__global__ __launch_bounds__(256)
void prew_fb(const float* __restrict__ noise, const float* __restrict__ wo,
             const float* __restrict__ so, float* __restrict__ W) {
    __shared__ __align__(16) float red[2][8][4][8];

    const int tid  = threadIdx.x;
    const int wave = tid >> 6;
    const int lane = tid & 63;
    const int e0   = tid << 2;

    float woa[4][OO];
    {
        float so8[OO];
        #pragma unroll
        for (int o = 0; o < OO; ++o) so8[o] = so[o] * NOISE_STD;
        #pragma unroll
        for (int e = 0; e < 4; ++e) {
            const float4 a4 = *(const float4*)(wo + (e0 + e) * OO);
            const float4 b4 = *(const float4*)(wo + (e0 + e) * OO + 4);
            woa[e][0] = a4.x * so8[0]; woa[e][1] = a4.y * so8[1];
            woa[e][2] = a4.z * so8[2]; woa[e][3] = a4.w * so8[3];
            woa[e][4] = b4.x * so8[4]; woa[e][5] = b4.y * so8[5];
            woa[e][6] = b4.z * so8[6]; woa[e][7] = b4.w * so8[7];
        }
    }

    const int row0 = blockIdx.x * 32;
    float4 nz[8], nzn[8];
    #pragma unroll
    for (int j = 0; j < 8; ++j)
        nz[j] = *(const float4*)(noise + (size_t)(row0 + j) * HH + e0);

    #pragma unroll
    for (int ph = 0; ph < 4; ++ph) {
        const int cur   = ph & 1;
        const int rbase = row0 + ph * 8;
        if (ph < 3) {
            #pragma unroll
            for (int j = 0; j < 8; ++j)
                nzn[j] = *(const float4*)(noise + (size_t)(rbase + 8 + j) * HH + e0);
        }
        #pragma unroll
        for (int j = 0; j < 8; ++j) {
            float op[OO];
            #pragma unroll
            for (int o = 0; o < OO; ++o)
                op[o] = fmaf(nz[j].x, woa[0][o], fmaf(nz[j].y, woa[1][o],
                        fmaf(nz[j].z, woa[2][o], nz[j].w * woa[3][o])));
            #pragma unroll
            for (int o = 0; o < OO; ++o) op[o] = wave_sum(op[o]);
            if (lane == 63) {
                *(float4*)&red[cur][j][wave][0] = make_float4(op[0], op[1], op[2], op[3]);
                *(float4*)&red[cur][j][wave][4] = make_float4(op[4], op[5], op[6], op[7]);
            }
        }
        block_sync_lds();
        if (tid < 64) {
            const int j = tid >> 3, o = tid & 7;
            W[(rbase + j) * OO + o] = (red[cur][j][0][o] + red[cur][j][1][o]) +
                                      (red[cur][j][2][o] + red[cur][j][3][o]);
        }
        #pragma unroll
        for (int j = 0; j < 8; ++j) nz[j] = nzn[j];
    }
}

__global__ __launch_bounds__(256, 1)
void rnn_fb(const float* __restrict__ x, const float* __restrict__ noise,
            const float* __restrict__ wi, const float* __restrict__ si,
            const float* __restrict__ mM, const float* __restrict__ nM,
            const float* __restrict__ bv, const float* __restrict__ wo,
            const float* __restrict__ so, const float* __restrict__ h0,
            const float* __restrict__ W, float* __restrict__ out) {
    __shared__ __align__(16) float lds_x[(TT + 1) * II];
    __shared__ __align__(16) float lds_W[TT * OO];
    __shared__ __align__(16) float lds_out[TT * OO];
    __shared__ __align__(16) float red[4][4][4];
    __shared__ __align__(16) float redc[4][104];
    __shared__ float ambx[104];

    const int tid  = threadIdx.x;
    const int b    = blockIdx.x;
    const int wave = tid >> 6;
    const int lane = tid & 63;
    const int e0   = tid << 2;
    const int oc   = tid & 7;

    {
        const float4* sx = (const float4*)(x + (size_t)b * (TT * II));
        const float4* sw = (const float4*)(W + (size_t)b * (TT * OO));
        float4* dx = (float4*)lds_x;
        float4* dw = (float4*)lds_W;
        #pragma unroll
        for (int k = 0; k < 8; ++k) {
            dx[k * 256 + tid] = sx[k * 256 + tid];
            dw[k * 256 + tid] = sw[k * 256 + tid];
        }
        if (tid < 2) dx[2048 + tid] = sx[2046 + tid];
    }

    float wia[II][4];
    v4f   wiac[II];
    #pragma unroll
    for (int i = 0; i < II; ++i) {
        const float s  = ALPHA * si[i];
        const float4 w = *(const float4*)(wi + i * HH + e0);
        wia[i][0] = w.x * s; wia[i][1] = w.y * s; wia[i][2] = w.z * s; wia[i][3] = w.w * s;
        wiac[i] = (v4f){wia[i][0], wia[i][1], wia[i][2], wia[i][3]};
    }
    float ma[4][RRK];
    v4f   nrv[4];
    v4f   mac[RRK];
    #pragma unroll
    for (int e = 0; e < 4; ++e) {
        const float4 m4 = *(const float4*)(mM + (e0 + e) * RRK);
        const float4 n4 = *(const float4*)(nM + (e0 + e) * RRK);
        const float cs = ALPHA / (float)HH;
        ma[e][0] = m4.x * cs; ma[e][1] = m4.y * cs; ma[e][2] = m4.z * cs; ma[e][3] = m4.w * cs;
        nrv[e] = (v4f){n4.x, n4.y, n4.z, n4.w};
    }
    #pragma unroll
    for (int q = 0; q < RRK; ++q)
        mac[q] = (v4f){ma[0][q], ma[1][q], ma[2][q], ma[3][q]};

    float woa[4][OO];
    {
        #pragma unroll
        for (int e = 0; e < 4; ++e) {
            const float4 a4 = *(const float4*)(wo + (e0 + e) * OO);
            const float4 b4 = *(const float4*)(wo + (e0 + e) * OO + 4);
            woa[e][0] = a4.x * so[0]; woa[e][1] = a4.y * so[1];
            woa[e][2] = a4.z * so[2]; woa[e][3] = a4.w * so[3];
            woa[e][4] = b4.x * so[4]; woa[e][5] = b4.y * so[5];
            woa[e][6] = b4.z * so[6]; woa[e][7] = b4.w * so[7];
        }
    }
    v4f tb2e, h, rr;
    {
        const v4f b4 = *(const v4f*)(bv + e0);
        tb2e = C2E * b4;
        h = *(const v4f*)(h0 + e0);
        v4f targ = C2E * h;
        rr.x = tanh_from_l2x(targ.x); rr.y = tanh_from_l2x(targ.y);
        rr.z = tanh_from_l2x(targ.z); rr.w = tanh_from_l2x(targ.w);
    }

    #pragma unroll
    for (int kg = 0; kg < 26; ++kg) {
        float p[4];
        #pragma unroll
        for (int u = 0; u < 4; ++u) {
            const int k = kg * 4 + u;
            float s;
            if (k < 32) {
                const int q = k >> 3, o = k & 7;
                s = fmaf(ma[0][q], woa[0][o], fmaf(ma[1][q], woa[1][o],
                    fmaf(ma[2][q], woa[2][o], ma[3][q] * woa[3][o])));
            } else if (k < 96) {
                const int i = (k - 32) >> 3, o = k & 7;
                s = fmaf(wia[i][0], woa[0][o], fmaf(wia[i][1], woa[1][o],
                    fmaf(wia[i][2], woa[2][o], wia[i][3] * woa[3][o])));
            } else {
                const int o = k - 96;
                s = fmaf(h.x, woa[0][o], fmaf(h.y, woa[1][o],
                    fmaf(h.z, woa[2][o], h.w * woa[3][o])));
            }
            p[u] = wave_sum(s);
        }
        if (lane == 63)
            *(float4*)&redc[wave][kg * 4] = make_float4(p[0], p[1], p[2], p[3]);
    }
    block_sync_lds();
    if (tid < 104)
        ambx[tid] = (redc[0][tid] + redc[1][tid]) + (redc[2][tid] + redc[3][tid]);
    __syncthreads();

    float Amr[RRK], Bxr[II], y;
    #pragma unroll
    for (int q = 0; q < RRK; ++q) Amr[q] = ambx[q * 8 + oc];
    #pragma unroll
    for (int i = 0; i < II; ++i) Bxr[i] = ambx[32 + i * 8 + oc];
    y = ambx[96 + oc];

    const float* nzp = noise + (size_t)b * (TT * HH) + e0;
    v4f nzb[4];
    #pragma unroll
    for (int j = 0; j < 4; ++j) nzb[j] = *(const v4f*)(nzp + j * HH);

    v4f xqc0 = *(const v4f*)&lds_x[0];
    v4f xqc1 = *(const v4f*)&lds_x[4];
    float wqc = lds_W[oc];

    for (int t0 = 0; t0 < TT; t0 += 4) {
        #pragma unroll
        for (int j = 0; j < 4; ++j) {
            const int t = t0 + j;
            const int tn = t + 1;
            const v4f xqn0 = *(const v4f*)&lds_x[tn * II];
            const v4f xqn1 = *(const v4f*)&lds_x[tn * II + 4];
            const float wqn = lds_W[(tn & (TT - 1)) * OO + oc];

            v4f vpv = rr.x * nrv[0];
            vpv += rr.y * nrv[1];
            vpv += rr.z * nrv[2];
            vpv += rr.w * nrv[3];
            float vp0 = wave_sum(vpv.x);
            float vp1 = wave_sum(vpv.y);
            float vp2 = wave_sum(vpv.z);
            float vp3 = wave_sum(vpv.w);
            if (lane == 63)
                *(float4*)&red[j][wave][0] = make_float4(vp0, vp1, vp2, vp3);

            float ybase = fmaf(xqc0.x, Bxr[0], wqc);
            ybase = fmaf(xqc0.y, Bxr[1], ybase);
            ybase = fmaf(xqc0.z, Bxr[2], ybase);
            ybase = fmaf(xqc0.w, Bxr[3], ybase);
            ybase = fmaf(xqc1.x, Bxr[4], ybase);
            ybase = fmaf(xqc1.y, Bxr[5], ybase);
            ybase = fmaf(xqc1.z, Bxr[6], ybase);
            ybase = fmaf(xqc1.w, Bxr[7], ybase);

            v4f auv = xqc0.x * wiac[0];
            auv += xqc0.y * wiac[1];
            auv += xqc0.z * wiac[2];
            auv += xqc0.w * wiac[3];
            auv += xqc1.x * wiac[4];
            auv += xqc1.y * wiac[5];
            auv += xqc1.z * wiac[6];
            auv += xqc1.w * wiac[7];

            block_sync_lds();

            const v4f s0 = *(const v4f*)&red[j][0][0];
            const v4f s1 = *(const v4f*)&red[j][1][0];
            const v4f s2 = *(const v4f*)&red[j][2][0];
            const v4f s3 = *(const v4f*)&red[j][3][0];
            const v4f vs = (s0 + s1) + (s2 + s3);

            v4f acc = auv;
            acc += vs.x * mac[0];
            acc += vs.y * mac[1];
            acc += vs.z * mac[2];
            acc += vs.w * mac[3];
            h = (1.0f - ALPHA) * h + acc;
            h += NOISE_STD * nzb[j];

            {
                float t4 = fmaf(vs.x, Amr[0], ybase);
                t4 = fmaf(vs.y, Amr[1], t4);
                t4 = fmaf(vs.z, Amr[2], t4);
                t4 = fmaf(vs.w, Amr[3], t4);
                y = fmaf(1.0f - ALPHA, y, t4);
                if (tid < OO) lds_out[t * OO + tid] = y;
            }

            nzb[j] = *(const v4f*)(nzp + ((t + 4) & (TT - 1)) * HH);

            {
                v4f targ = C2E * h + tb2e;
                rr.x = tanh_from_l2x(targ.x);
                rr.y = tanh_from_l2x(targ.y);
                rr.z = tanh_from_l2x(targ.z);
                rr.w = tanh_from_l2x(targ.w);
            }
            xqc0 = xqn0; xqc1 = xqn1; wqc = wqn;
        }
    }

    __syncthreads();
    {
        float4* dst = (float4*)(out + (size_t)b * (TT * OO));
        const float4* srcv = (const float4*)lds_out;
        #pragma unroll
        for (int k = 0; k < 8; ++k)
            dst[k * 256 + tid] = srcv[k * 256 + tid];
    }
}

extern "C" void kernel_launch(void* const* d_in, const int* in_sizes, int n_in,
                              void* d_out, int out_size, void* d_ws, size_t ws_size,
                              hipStream_t stream) {
    const float* x     = (const float*)d_in[0];
    const float* noise = (const float*)d_in[1];
    const float* wi    = (const float*)d_in[2];
    const float* si    = (const float*)d_in[3];
    const float* mM    = (const float*)d_in[4];
    const float* nM    = (const float*)d_in[5];
    const float* bv    = (const float*)d_in[6];
    const float* wo    = (const float*)d_in[7];
    const float* so    = (const float*)d_in[8];
    const float* h0    = (const float*)d_in[9];
    float* out = (float*)d_out;

    const size_t needD = (size_t)BB * TT * HH * sizeof(float);   // 256 MB
    const size_t needS = (size_t)BB * TT * OO * sizeof(float);   // 2 MB

    if (ws_size >= needD + needS) {
        float* dbuf = (float*)d_ws;
        float* sb   = dbuf + (size_t)BB * TT * HH;
        pre_d_kernel<<<dim3(2048), dim3(256), 0, stream>>>(
            x, noise, wi, si, wo, so, dbuf, sb);
        rnn_d_kernel<<<dim3(BB), dim3(64), 0, stream>>>(
            dbuf, sb, mM, nM, bv, wo, so, h0, out);
    } else {
        float* W = (float*)d_ws;   // 2 MB
        prew_fb<<<dim3(2048), dim3(256), 0, stream>>>(noise, wo, so, W);
        rnn_fb<<<dim3(BB), dim3(256), 0, stream>>>(
            x, noise, wi, si, mM, nM, bv, wo, so, h0, W, out);
    }
}